// Round 1
// baseline (83.585 us; speedup 1.0000x reference)
//
#include <hip/hip_runtime.h>
#include <hip/hip_bf16.h>

// Problem constants (reference: B=64, Z=512, H=W=32 -> N=1024, Q=1)
#define B_ 64
#define Z_ 512
#define N_ 1024
#define LAM 1e-3f
#define NQ 8        // n-slabs per batch sample (one block each)
#define NR 128      // columns (pixels) per block  = N_/NQ
#define TN 32       // columns per LDS tile
#define NT 4        // tiles per block = NR/TN
#define TH 1024     // threads per block

// Block (b, nq): owns pixel columns [nq*128, nq*128+128) of sample b.
// For each 32-column tile: stage x[b, 0:512, n0:n0+32] into LDS transposed
// as lds_x[j][z] (z padded to 513 words -> all phases conflict-free),
// phase A: s[j] = sum_z W[z]*x[z,j] -> h=sigmoid(s)
// phase B: xh[z] += sum_j x[z,j]*h[j]   (register accumulator per thread)
// End: atomicAdd partial xh into out; write partial sum(h^2) to ws.
__global__ __launch_bounds__(TH, 8) void elm_k1(
    const float* __restrict__ x, const float* __restrict__ Wh,
    float* __restrict__ out, float* __restrict__ gws) {
  __shared__ float lds_x[TN][513];   // 65,664 B
  __shared__ float w_lds[Z_];        //  2,048 B
  __shared__ float part[TH];         //  4,096 B (phase-A partials, then xh combine)
  __shared__ float h_all[NR];        //    512 B
  __shared__ float gred[2];

  const int t   = threadIdx.x;
  const int bid = blockIdx.x;
  const int b   = bid >> 3;
  const int nq  = bid & 7;
  const int nbase = nq * NR;
  const size_t xbase = (size_t)b * (size_t)(Z_ * N_);

  if (t < Z_) w_lds[t] = Wh[t];      // W is [1, Z]

  const int zB = t & 511;            // phase-B: this thread's z row
  const int jh = t >> 9;             // phase-B: which half of the 32 columns
  float acc = 0.f;                   // partial xh[b, zB] over this block's columns

  for (int tile = 0; tile < NT; ++tile) {
    const int n0 = nbase + tile * TN;
    __syncthreads();                 // prev phase-B readers done; w_lds ready (tile 0)

    // ---- stage 32 cols x 512 z (64 KiB), transposed into lds_x[j][z] ----
    // float4 index f in [0,4096): z = f>>3, col-group jg = f&7 (4 cols each)
#pragma unroll
    for (int k = 0; k < 4; ++k) {
      const int f  = t + k * TH;
      const int z  = f >> 3;
      const int jg = f & 7;
      const float4 v = *reinterpret_cast<const float4*>(
          x + xbase + (size_t)z * N_ + (n0 + jg * 4));
      const int jc = jg * 4;
      lds_x[jc + 0][z] = v.x;
      lds_x[jc + 1][z] = v.y;
      lds_x[jc + 2][z] = v.z;
      lds_x[jc + 3][z] = v.w;
    }
    __syncthreads();

    // ---- phase A: s[j] = sum_z W[z]*x[j][z]; 32 slices of 16 z each ----
    {
      const int j  = t & 31;
      const int sl = t >> 5;
      const int z0 = sl * 16;
      float s = 0.f;
#pragma unroll
      for (int k = 0; k < 16; ++k) s += w_lds[z0 + k] * lds_x[j][z0 + k];
      part[sl * 32 + j] = s;
    }
    __syncthreads();
    if (t < TN) {
      float s = 0.f;
#pragma unroll
      for (int sl = 0; sl < 32; ++sl) s += part[sl * 32 + t];
      h_all[tile * TN + t] = 1.f / (1.f + __expf(-s));
    }
    __syncthreads();

    // ---- phase B: acc += sum over this tile's 16 cols (per jh half) ----
    {
      float a = 0.f;
#pragma unroll
      for (int k = 0; k < 16; ++k) {
        const int j = jh * 16 + k;
        a += lds_x[j][zB] * h_all[tile * TN + j];
      }
      acc += a;
    }
  }

  // ---- combine the two jh halves and push partial xh into out ----
  part[t] = acc;                     // part free since last reduce had a barrier
  __syncthreads();
  if (t < 512) {
    const float v = part[t] + part[t + 512];
    atomicAdd(&out[b * Z_ + t], v);
  }

  // ---- partial g = sum over this block's 128 h^2 ----
  if (t < NR) {
    float q = h_all[t];
    q = q * q;
#pragma unroll
    for (int off = 32; off > 0; off >>= 1) q += __shfl_down(q, off);
    if ((t & 63) == 0) gred[t >> 6] = q;
  }
  __syncthreads();
  if (t == 0) gws[bid] = gred[0] + gred[1];
}

// out[b, z] /= (sum_nq g_part[b, nq] + LAM)
__global__ void elm_k2(float* __restrict__ out, const float* __restrict__ gws) {
  const int b = blockIdx.x;
  __shared__ float ginv;
  if (threadIdx.x == 0) {
    float g = LAM;
#pragma unroll
    for (int i = 0; i < NQ; ++i) g += gws[b * NQ + i];
    ginv = 1.f / g;
  }
  __syncthreads();
  out[b * Z_ + threadIdx.x] *= ginv;
}

extern "C" void kernel_launch(void* const* d_in, const int* in_sizes, int n_in,
                              void* d_out, int out_size, void* d_ws, size_t ws_size,
                              hipStream_t stream) {
  const float* x  = (const float*)d_in[0];
  const float* Wh = (const float*)d_in[1];
  float* out = (float*)d_out;
  float* gws = (float*)d_ws;   // B_*NQ = 512 floats

  hipMemsetAsync(out, 0, (size_t)B_ * Z_ * sizeof(float), stream);
  elm_k1<<<dim3(B_ * NQ), dim3(TH), 0, stream>>>(x, Wh, out, gws);
  elm_k2<<<dim3(B_), dim3(Z_), 0, stream>>>(out, gws);
}

// Round 2
// 33.616 us; speedup vs baseline: 2.4865x; 2.4865x over previous
//
#include <hip/hip_runtime.h>
#include <hip/hip_bf16.h>

// Problem constants (reference: B=64, Z=512, H=W=32 -> N=1024, Q=1)
#define B_ 64
#define Z_ 512
#define N_ 1024
#define LAM 1e-3f
#define NQ 16       // column-slabs per batch sample (one block each)
#define NR 64       // pixel columns per block  = N_/NQ
#define NTL 2       // 32-column tiles per block
#define TH 1024     // threads per block

// Block (b, nq): owns pixel columns [nq*64, nq*64+64) of sample b.
// All of the block's x slab (512 z x 64 cols = 128 KB) is loaded into
// REGISTERS (8 float4/thread), issued upfront with no barriers in between.
//   thread t: jg = t&7 (column group of 4), zr = t>>3; covers z = zr+128k, k=0..3
// phase A: s[c] = sum_z W[z] x[z,c]  -> per-thread partials, shfl_xor(8,16,32)
//          wave-reduce, 16x64 LDS partial array, 64-thread final reduce -> h
// phase B: xh[z] += sum_c x[z,c] h[c] -> register FMA, shfl_xor(1,2,4) over the
//          8 consecutive lanes sharing z, lane jg==0 atomicAdds into out.
// Only 2 __syncthreads per block; no load crosses a barrier.
__global__ __launch_bounds__(TH) void elm_k1(
    const float* __restrict__ x, const float* __restrict__ Wh,
    float* __restrict__ out, float* __restrict__ gws) {
  __shared__ float part[16][NR];   // per-wave s partials (4 KB)
  __shared__ float h_lds[NR];

  const int t   = threadIdx.x;
  const int bid = blockIdx.x;
  const int b   = bid >> 4;
  const int nq  = bid & 15;
  const int nbase = nq * NR;
  const size_t xb = (size_t)b * (size_t)(Z_ * N_);
  const int jg = t & 7;            // column group (4 cols)
  const int zr = t >> 3;           // z residue [0,128)
  const int wv = t >> 6;           // wave id [0,16)
  const int ln = t & 63;           // lane

  // ---- load the whole slab into registers: v[tl][k] = x[b, zr+128k, nbase+tl*32+jg*4 ..+3]
  float4 v[NTL][4];
#pragma unroll
  for (int tl = 0; tl < NTL; ++tl)
#pragma unroll
    for (int k = 0; k < 4; ++k)
      v[tl][k] = *reinterpret_cast<const float4*>(
          x + xb + (size_t)(zr + 128 * k) * N_ + (nbase + tl * 32 + jg * 4));

  float w[4];
#pragma unroll
  for (int k = 0; k < 4; ++k) w[k] = Wh[zr + 128 * k];

  // ---- phase A: per-thread partial s over this thread's 4 z's ----
  float sp[NTL][4];
#pragma unroll
  for (int tl = 0; tl < NTL; ++tl)
#pragma unroll
    for (int i = 0; i < 4; ++i) {
      const float* vp0 = reinterpret_cast<const float*>(&v[tl][0]);
      const float* vp1 = reinterpret_cast<const float*>(&v[tl][1]);
      const float* vp2 = reinterpret_cast<const float*>(&v[tl][2]);
      const float* vp3 = reinterpret_cast<const float*>(&v[tl][3]);
      sp[tl][i] = w[0] * vp0[i] + w[1] * vp1[i] + w[2] * vp2[i] + w[3] * vp3[i];
    }
  // wave reduce across lanes differing in bits 3..5 (same jg within wave)
#pragma unroll
  for (int tl = 0; tl < NTL; ++tl)
#pragma unroll
    for (int i = 0; i < 4; ++i) {
      float s = sp[tl][i];
      s += __shfl_xor(s, 8);
      s += __shfl_xor(s, 16);
      s += __shfl_xor(s, 32);
      sp[tl][i] = s;
    }
  if (ln < 8) {
#pragma unroll
    for (int tl = 0; tl < NTL; ++tl)
#pragma unroll
      for (int i = 0; i < 4; ++i)
        part[wv][tl * 32 + ln * 4 + i] = sp[tl][i];
  }
  __syncthreads();

  // ---- final s reduce over 16 waves, h = sigmoid(s), partial g ----
  if (t < NR) {
    float s = 0.f;
#pragma unroll
    for (int w16 = 0; w16 < 16; ++w16) s += part[w16][t];
    const float h = 1.f / (1.f + __expf(-s));
    h_lds[t] = h;
    float q = h * h;                 // all t<64 are wave 0
    q += __shfl_xor(q, 1);
    q += __shfl_xor(q, 2);
    q += __shfl_xor(q, 4);
    q += __shfl_xor(q, 8);
    q += __shfl_xor(q, 16);
    q += __shfl_xor(q, 32);
    if (t == 0) gws[bid] = q;
  }
  __syncthreads();

  // ---- phase B: xh[z] partials from registers ----
  float acc[4] = {0.f, 0.f, 0.f, 0.f};
#pragma unroll
  for (int tl = 0; tl < NTL; ++tl)
#pragma unroll
    for (int i = 0; i < 4; ++i) {
      const float h = h_lds[tl * 32 + jg * 4 + i];
      const float* vp0 = reinterpret_cast<const float*>(&v[tl][0]);
      const float* vp1 = reinterpret_cast<const float*>(&v[tl][1]);
      const float* vp2 = reinterpret_cast<const float*>(&v[tl][2]);
      const float* vp3 = reinterpret_cast<const float*>(&v[tl][3]);
      acc[0] += h * vp0[i];
      acc[1] += h * vp1[i];
      acc[2] += h * vp2[i];
      acc[3] += h * vp3[i];
    }
#pragma unroll
  for (int k = 0; k < 4; ++k) {
    float a = acc[k];
    a += __shfl_xor(a, 1);
    a += __shfl_xor(a, 2);
    a += __shfl_xor(a, 4);
    if (jg == 0) atomicAdd(&out[b * Z_ + zr + 128 * k], a);
  }
}

// out[b, z] /= (sum_nq g_part[b, nq] + LAM)
__global__ void elm_k2(float* __restrict__ out, const float* __restrict__ gws) {
  const int b = blockIdx.x;
  __shared__ float ginv;
  if (threadIdx.x == 0) {
    float g = LAM;
#pragma unroll
    for (int i = 0; i < NQ; ++i) g += gws[b * NQ + i];
    ginv = 1.f / g;
  }
  __syncthreads();
  out[b * Z_ + threadIdx.x] *= ginv;
}

extern "C" void kernel_launch(void* const* d_in, const int* in_sizes, int n_in,
                              void* d_out, int out_size, void* d_ws, size_t ws_size,
                              hipStream_t stream) {
  const float* x  = (const float*)d_in[0];
  const float* Wh = (const float*)d_in[1];
  float* out = (float*)d_out;
  float* gws = (float*)d_ws;   // B_*NQ = 1024 floats

  hipMemsetAsync(out, 0, (size_t)B_ * Z_ * sizeof(float), stream);
  elm_k1<<<dim3(B_ * NQ), dim3(TH), 0, stream>>>(x, Wh, out, gws);
  elm_k2<<<dim3(B_), dim3(Z_), 0, stream>>>(out, gws);
}

// Round 3
// 30.887 us; speedup vs baseline: 2.7061x; 1.0883x over previous
//
#include <hip/hip_runtime.h>
#include <hip/hip_bf16.h>

// Problem constants (reference: B=64, Z=512, H=W=32 -> N=1024, Q=1)
#define B_ 64
#define Z_ 512
#define N_ 1024
#define LAM 1e-3f
#define NQ 32       // column-slabs per batch sample (one block each)
#define NC 32       // pixel columns per block = N_/NQ
#define TH 512      // threads per block
#define WS_XH (B_ * NQ * Z_)   // float count of xh-partial region in d_ws

// Block (b, nq): owns pixel columns [nq*32, nq*32+32) of sample b.
// Slab x[b, :, cols] (512 z x 32 cols = 64 KB) lives in REGISTERS:
//   thread t: jg = t&7 (4-col group), zr = t>>3 in [0,64); v[k] = float4 at
//   z = zr + 64k, k = 0..7. All 8 loads independent, issued upfront.
// phase A: s[c] = sum_z W[z] x[z,c]; per-thread partials, shfl_xor(8,16,32)
//   wave-reduce, 8x32 LDS partials, 32-thread final -> h = sigmoid(s)
// phase B: xh[z] = sum_c x[z,c] h[c]; register FMA, shfl_xor(1,2,4) over jg,
//   lane jg==0 stores the per-block partial to ws (no atomics, no memset).
// 2 barriers; no global atomics; 64-VGPR cap for 8 waves/SIMD.
__global__ __launch_bounds__(TH, 8) void elm_k1(
    const float* __restrict__ x, const float* __restrict__ Wh,
    float* __restrict__ pxh, float* __restrict__ gws) {
  __shared__ float part[8][NC];   // per-wave s partials (1 KB)
  __shared__ float h_lds[NC];

  const int t   = threadIdx.x;
  const int bid = blockIdx.x;
  const int b   = bid >> 5;
  const int nq  = bid & 31;
  const int jg  = t & 7;          // column group (4 cols)
  const int zr  = t >> 3;         // z residue [0,64)
  const int wv  = t >> 6;         // wave id [0,8)
  const int ln  = t & 63;

  const float* xp = x + (size_t)b * (Z_ * N_) + (size_t)zr * N_ + (nq * NC + jg * 4);

  float4 v[8];
#pragma unroll
  for (int k = 0; k < 8; ++k)
    v[k] = *reinterpret_cast<const float4*>(xp + (size_t)(64 * k) * N_);

  float w[8];
#pragma unroll
  for (int k = 0; k < 8; ++k) w[k] = Wh[zr + 64 * k];

  // ---- phase A ----
  float sp[4];
#pragma unroll
  for (int i = 0; i < 4; ++i) {
    float s = 0.f;
#pragma unroll
    for (int k = 0; k < 8; ++k) s += w[k] * reinterpret_cast<const float*>(&v[k])[i];
    s += __shfl_xor(s, 8);
    s += __shfl_xor(s, 16);
    s += __shfl_xor(s, 32);
    sp[i] = s;
  }
  if (ln < 8) {
#pragma unroll
    for (int i = 0; i < 4; ++i) part[wv][ln * 4 + i] = sp[i];
  }
  __syncthreads();

  if (t < NC) {
    float s = 0.f;
#pragma unroll
    for (int w8 = 0; w8 < 8; ++w8) s += part[w8][t];
    const float h = 1.f / (1.f + __expf(-s));
    h_lds[t] = h;
    float q = h * h;               // lanes 0..31 of wave 0
    q += __shfl_xor(q, 1);
    q += __shfl_xor(q, 2);
    q += __shfl_xor(q, 4);
    q += __shfl_xor(q, 8);
    q += __shfl_xor(q, 16);
    if (t == 0) gws[bid] = q;
  }
  __syncthreads();

  // ---- phase B ----
  float acc[8] = {0.f, 0.f, 0.f, 0.f, 0.f, 0.f, 0.f, 0.f};
#pragma unroll
  for (int i = 0; i < 4; ++i) {
    const float h = h_lds[jg * 4 + i];
#pragma unroll
    for (int k = 0; k < 8; ++k) acc[k] += h * reinterpret_cast<const float*>(&v[k])[i];
  }
#pragma unroll
  for (int k = 0; k < 8; ++k) {
    float a = acc[k];
    a += __shfl_xor(a, 1);
    a += __shfl_xor(a, 2);
    a += __shfl_xor(a, 4);
    if (jg == 0) pxh[(size_t)bid * Z_ + zr + 64 * k] = a;
  }
}

// out[b, z] = (sum_nq pxh[b,nq,z]) / (sum_nq g[b,nq] + LAM)
__global__ __launch_bounds__(Z_) void elm_k2(
    const float* __restrict__ pxh, const float* __restrict__ gws,
    float* __restrict__ out) {
  const int b = blockIdx.x;
  const int t = threadIdx.x;
  __shared__ float ginv;
  if (t < 32) {
    float g = gws[b * NQ + t];
    g += __shfl_xor(g, 1);
    g += __shfl_xor(g, 2);
    g += __shfl_xor(g, 4);
    g += __shfl_xor(g, 8);
    g += __shfl_xor(g, 16);
    if (t == 0) ginv = 1.f / (g + LAM);
  }
  __syncthreads();
  float s = 0.f;
#pragma unroll
  for (int nq = 0; nq < NQ; ++nq) s += pxh[((size_t)b * NQ + nq) * Z_ + t];
  out[b * Z_ + t] = s * ginv;
}

extern "C" void kernel_launch(void* const* d_in, const int* in_sizes, int n_in,
                              void* d_out, int out_size, void* d_ws, size_t ws_size,
                              hipStream_t stream) {
  const float* x  = (const float*)d_in[0];
  const float* Wh = (const float*)d_in[1];
  float* out = (float*)d_out;
  float* pxh = (float*)d_ws;            // B_*NQ*Z_ floats = 4 MB
  float* gws = (float*)d_ws + WS_XH;    // B_*NQ floats

  elm_k1<<<dim3(B_ * NQ), dim3(TH), 0, stream>>>(x, Wh, pxh, gws);
  elm_k2<<<dim3(B_), dim3(Z_), 0, stream>>>(pxh, gws, out);
}